// Round 3
// baseline (1142.540 us; speedup 1.0000x reference)
//
#include <hip/hip_runtime.h>
#include <stdint.h>

#define B_ROWS 32768
#define F_DIM  1024
#define H_DIM  512

typedef __attribute__((ext_vector_type(4))) float    floatx4;
typedef __attribute__((ext_vector_type(2))) __fp16   fp16x2;
typedef __attribute__((ext_vector_type(8))) _Float16 halfx8;

__device__ __forceinline__ void async_load16(const void* g, void* l) {
    __builtin_amdgcn_global_load_lds(
        (const __attribute__((address_space(1))) void*)g,
        (__attribute__((address_space(3))) void*)l, 16, 0, 0);
}

// ---------------------------------------------------------------- Wlin -> f16
__global__ __launch_bounds__(256) void k_cvt(const float* __restrict__ src,
                                             ushort* __restrict__ dst, int n) {
    int i = (blockIdx.x * 256 + threadIdx.x) * 4;
    if (i >= n) return;
    floatx4 f = *(const floatx4*)(src + i);
    union { _Float16 h[4]; ushort4 u; } o;
    o.h[0] = (_Float16)f.x; o.h[1] = (_Float16)f.y;
    o.h[2] = (_Float16)f.z; o.h[3] = (_Float16)f.w;
    *(ushort4*)(dst + i) = o.u;
}

// ---------------------------------------------------------- h = w @ Wlin^T + blin
// 128x128 tile, BK=64. A (w_k) staged f32 via global_load_lds, converted to f16
// at fragment read (v_cvt_pkrtz). B (Wlin) pre-converted to f16.
// 4 waves; wave w owns rows [w*32, w*32+32) x all 128 cols -> A converted once/wave.
__global__ __launch_bounds__(256) void k_gemm_h(
    const float* __restrict__ w0, const float* __restrict__ w1,
    const float* __restrict__ w2, const float* __restrict__ w3,
    const ushort* __restrict__ Wlin16, const float* __restrict__ blin,
    ushort* __restrict__ h16)
{
    __shared__ float  As[128 * 64];   // 32 KiB, row-major [row][64]
    __shared__ ushort Bs[128 * 64];   // 16 KiB, row-major [n][64]

    const int tid     = threadIdx.x;
    const int bx      = blockIdx.x;
    const int colTile = bx & 15;      // 16 col tiles (2048 cols total)
    const int rowTile = bx >> 4;      // 256 row tiles
    const int k       = colTile >> 2;           // head index 0..3
    const int rowBase = rowTile * 128;
    const int colBase = colTile * 128;          // in [0,2048)
    const int nBase   = (colTile & 3) * 128;    // within this k's 512

    const float* A = (k == 0) ? w0 : (k == 1) ? w1 : (k == 2) ? w2 : w3;

    // staging: A rows = 256B (16 lanes x 16B), 16 rows/issue, 8 issues
    // per-wave LDS dest = uniform base + lane*16B (global_load_lds constraint)
    const int arow = tid >> 4;
    const int acol = (tid & 15) << 2;
    // staging: B rows = 128B (8 lanes x 16B), 32 rows/issue, 4 issues
    const int brow = tid >> 3;
    const int bcol = (tid & 7) << 3;

    const float*  gA0 = A      + (size_t)(rowBase + arow) * F_DIM + acol;
    const ushort* gB0 = Wlin16 + (size_t)(k * H_DIM + nBase + brow) * F_DIM + bcol;
    float*  lA = &As[arow * 64 + acol];
    ushort* lB = &Bs[brow * 64 + bcol];

    const int wv = tid >> 6;
    const int ln = tid & 63;
    const int lr = ln & 15;
    const int lq = ln >> 4;

    floatx4 acc[2][8] = {};

    for (int kc = 0; kc < F_DIM; kc += 64) {
        __syncthreads();   // prior compute done before overwriting LDS
        #pragma unroll
        for (int it = 0; it < 8; ++it)
            async_load16(gA0 + kc + it * 16 * F_DIM, lA + it * 16 * 64);
        #pragma unroll
        for (int it = 0; it < 4; ++it)
            async_load16(gB0 + kc + it * 32 * F_DIM, lB + it * 32 * 64);
        __syncthreads();   // drains vmcnt(0)

        #pragma unroll
        for (int ks = 0; ks < 2; ++ks) {
            halfx8 af[2];
            #pragma unroll
            for (int i = 0; i < 2; ++i) {
                const float* ap = &As[(wv * 32 + i * 16 + lr) * 64 + ks * 32 + lq * 8];
                floatx4 f0 = *(const floatx4*)ap;
                floatx4 f1 = *(const floatx4*)(ap + 4);
                union { fp16x2 h2[4]; halfx8 h8; } u;
                u.h2[0] = __builtin_amdgcn_cvt_pkrtz(f0.x, f0.y);
                u.h2[1] = __builtin_amdgcn_cvt_pkrtz(f0.z, f0.w);
                u.h2[2] = __builtin_amdgcn_cvt_pkrtz(f1.x, f1.y);
                u.h2[3] = __builtin_amdgcn_cvt_pkrtz(f1.z, f1.w);
                af[i] = u.h8;
            }
            #pragma unroll
            for (int j = 0; j < 8; ++j) {
                const halfx8 bf = *(const halfx8*)&Bs[(j * 16 + lr) * 64 + ks * 32 + lq * 8];
                acc[0][j] = __builtin_amdgcn_mfma_f32_16x16x32_f16(af[0], bf, acc[0][j], 0, 0, 0);
                acc[1][j] = __builtin_amdgcn_mfma_f32_16x16x32_f16(af[1], bf, acc[1][j], 0, 0, 0);
            }
        }
    }

    // epilogue: +blin, store f16 h. C/D: col=lane&15, row=(lane>>4)*4+reg
    const float* blk = blin + k * H_DIM + nBase;
    #pragma unroll
    for (int j = 0; j < 8; ++j) {
        const int c = j * 16 + lr;
        const float bl = blk[c];
        #pragma unroll
        for (int i = 0; i < 2; ++i) {
            const int r0 = rowBase + wv * 32 + i * 16 + lq * 4;
            #pragma unroll
            for (int r = 0; r < 4; ++r) {
                union { _Float16 f; ushort u; } cv;
                cv.f = (_Float16)(acc[i][j][r] + bl);
                h16[(size_t)(r0 + r) * 2048 + colBase + c] = cv.u;
            }
        }
    }
}

// ------------------------------------------------- q,k,v = h @ W{q,k,v}^T + b
// one wave per (b,k); half-wave (32 lanes) per output d, two d's in flight.
__global__ __launch_bounds__(256) void k_qkv(
    const ushort* __restrict__ h16,
    const float* __restrict__ Wq, const float* __restrict__ Wk, const float* __restrict__ Wv,
    const float* __restrict__ bq, const float* __restrict__ bk, const float* __restrict__ bv,
    float* __restrict__ qkv)
{
    const int wv    = threadIdx.x >> 6;
    const int ln    = threadIdx.x & 63;
    const int omega = blockIdx.x * 4 + wv;    // 0 .. B*4-1
    const int b     = omega >> 2;
    const int k     = omega & 3;
    const int g     = ln >> 5;                // half-wave id
    const int l32   = ln & 31;

    const ushort* hp = h16 + (size_t)b * 2048 + k * 512 + l32 * 16;
    union { uint4 u; halfx8 h8; } ua, ub;
    ua.u = *(const uint4*)hp;
    ub.u = *(const uint4*)(hp + 8);
    float hf[16];
    #pragma unroll
    for (int i = 0; i < 8; ++i) { hf[i] = (float)ua.h8[i]; hf[8 + i] = (float)ub.h8[i]; }

    float* out = qkv + (size_t)b * 120 + k * 30;
    #pragma unroll 1
    for (int dp = 0; dp < 15; ++dp) {
        const int d = dp * 2 + g;             // per-half-wave output index
        const float* wbase; float bias;
        if (d < 10)      { wbase = Wq + (size_t)(k * 10 + d) * 512;      bias = bq[k * 10 + d]; }
        else if (d < 20) { wbase = Wk + (size_t)(k * 10 + d - 10) * 512; bias = bk[k * 10 + d - 10]; }
        else             { wbase = Wv + (size_t)(k * 10 + d - 20) * 512; bias = bv[k * 10 + d - 20]; }
        const float* wp = wbase + l32 * 16;
        float s = 0.f;
        #pragma unroll
        for (int i = 0; i < 16; i += 4) {
            const floatx4 w4 = *(const floatx4*)(wp + i);
            s += hf[i] * w4.x + hf[i+1] * w4.y + hf[i+2] * w4.z + hf[i+3] * w4.w;
        }
        s += __shfl_xor(s, 16, 64);
        s += __shfl_xor(s, 8, 64);
        s += __shfl_xor(s, 4, 64);
        s += __shfl_xor(s, 2, 64);
        s += __shfl_xor(s, 1, 64);
        if (l32 == 0) out[d] = s + bias;
    }
}

// -------------------------------------------- per-b attention + heads epilogue
__global__ __launch_bounds__(256) void k_final(
    const float* __restrict__ qkv, const float* __restrict__ Wfin,
    const float* __restrict__ bfin,
    float* __restrict__ outputs, float* __restrict__ attn)
{
    __shared__ float sW[400];
    __shared__ float sb[40];
    const int t = threadIdx.x;
    for (int i = t; i < 400; i += 256) sW[i] = Wfin[i];   // FIX R2: 400 > blockDim
    if (t < 40) sb[t] = bfin[t];
    __syncthreads();

    const int b = blockIdx.x * 256 + t;
    const float* p = qkv + (size_t)b * 120;
    float q[4][10], kk[4][10], v0[10];
    #pragma unroll
    for (int k = 0; k < 4; ++k)
        #pragma unroll
        for (int e = 0; e < 10; ++e) {
            q[k][e]  = p[k * 30 + e];
            kk[k][e] = p[k * 30 + 10 + e];
        }
    #pragma unroll
    for (int m = 0; m < 10; ++m) v0[m] = p[20 + m];   // v, head 0

    float out0[10];
    #pragma unroll
    for (int e = 0; e < 10; ++e) out0[e] = 0.f;
    float* ab = attn + (size_t)b * 100;
    const float inv = 0.31622776601683794f;  // 1/sqrt(10)

    // attn[b,e,m] = softmax over e (axis=1) of (sum_k q[k][e]*kk[k][m])/sqrt(E)
    #pragma unroll
    for (int m = 0; m < 10; ++m) {
        float col[10]; float mx = -1e30f;
        #pragma unroll
        for (int e = 0; e < 10; ++e) {
            col[e] = (q[0][e]*kk[0][m] + q[1][e]*kk[1][m]
                    + q[2][e]*kk[2][m] + q[3][e]*kk[3][m]) * inv;
            mx = fmaxf(mx, col[e]);
        }
        float s = 0.f;
        #pragma unroll
        for (int e = 0; e < 10; ++e) { col[e] = __expf(col[e] - mx); s += col[e]; }
        const float r = 1.f / s;
        #pragma unroll
        for (int e = 0; e < 10; ++e) {
            const float a = col[e] * r;
            ab[e * 10 + m] = a;
            out0[e] += a * v0[m];     // att_out[b,0,e] accumulation
        }
    }

    float oc[10];
    #pragma unroll
    for (int c = 0; c < 10; ++c) oc[c] = 0.f;
    #pragma unroll
    for (int k = 0; k < 4; ++k) {
        float lg[10]; float mx = -1e30f;
        #pragma unroll
        for (int c = 0; c < 10; ++c) {
            float s = sb[k * 10 + c];
            #pragma unroll
            for (int e = 0; e < 10; ++e) s += out0[e] * sW[(k * 10 + c) * 10 + e];
            lg[c] = s; mx = fmaxf(mx, s);
        }
        float s = 0.f;
        #pragma unroll
        for (int c = 0; c < 10; ++c) { lg[c] = __expf(lg[c] - mx); s += lg[c]; }
        const float r = 0.25f / s;
        #pragma unroll
        for (int c = 0; c < 10; ++c) oc[c] += lg[c] * r;
    }
    #pragma unroll
    for (int c = 0; c < 10; ++c) outputs[(size_t)b * 10 + c] = oc[c];
}

extern "C" void kernel_launch(void* const* d_in, const int* in_sizes, int n_in,
                              void* d_out, int out_size, void* d_ws, size_t ws_size,
                              hipStream_t stream) {
    const float* w0   = (const float*)d_in[0];
    const float* w1   = (const float*)d_in[1];
    const float* w2   = (const float*)d_in[2];
    const float* w3   = (const float*)d_in[3];
    const float* Wlin = (const float*)d_in[4];
    const float* blin = (const float*)d_in[5];
    const float* Wq   = (const float*)d_in[6];
    const float* bq   = (const float*)d_in[7];
    const float* Wk   = (const float*)d_in[8];
    const float* bk   = (const float*)d_in[9];
    const float* Wv   = (const float*)d_in[10];
    const float* bv   = (const float*)d_in[11];
    const float* Wfin = (const float*)d_in[12];
    const float* bfin = (const float*)d_in[13];

    char* ws = (char*)d_ws;
    ushort* Wlin16 = (ushort*)ws;                                   // 4 MiB
    ushort* h16    = (ushort*)(ws + ((size_t)4 << 20));             // 128 MiB
    float*  qkv    = (float*)(ws + ((size_t)4 << 20) + ((size_t)B_ROWS * 2048 * 2)); // 15 MiB

    float* outputs = (float*)d_out;
    float* attn    = outputs + (size_t)B_ROWS * 10;

    k_cvt   <<<2048,  256, 0, stream>>>(Wlin, Wlin16, 4 * H_DIM * F_DIM);
    k_gemm_h<<<4096,  256, 0, stream>>>(w0, w1, w2, w3, Wlin16, blin, h16);
    k_qkv   <<<32768, 256, 0, stream>>>(h16, Wq, Wk, Wv, bq, bk, bv, qkv);
    k_final <<<128,   256, 0, stream>>>(qkv, Wfin, bfin, outputs, attn);
}